// Round 2
// baseline (3687.320 us; speedup 1.0000x reference)
//
#include <hip/hip_runtime.h>
#include <hip/hip_bf16.h>

#define B_ 128
#define S_ 256
#define I_ 512
#define H_ 1024

typedef float  f32x4  __attribute__((ext_vector_type(4)));
typedef __bf16 bf16x8 __attribute__((ext_vector_type(8)));
typedef unsigned short u16x8 __attribute__((ext_vector_type(8)));

__device__ __forceinline__ unsigned short f2bf(float f) {
    unsigned u = __float_as_uint(f);
    unsigned r = (u + 0x7fffu + ((u >> 16) & 1u)) >> 16;   // RNE
    return (unsigned short)r;
}
__device__ __forceinline__ float bf2f(unsigned short s) {
    return __uint_as_float(((unsigned)s) << 16);
}

// ---------------------------------------------------------------------------
// Column mapping (4 h-cols per p, 256 p-groups): B/C tile col c:
//   c 0-3 -> r-gate row p*4+c ; c 4-7 -> z-gate H+... ; c 8-11 -> n-gate 2H+...
//   c 12 -> Wa_h (hi in bhi, lo in blo)  => acc col 12 = h . Wa_h  (sh)
//   c 13-15 -> zero pad.
// ---------------------------------------------------------------------------

// Pack W_ih [3H, I] into per-colgroup B-frag order: [p 256][ks 16][lane 64][8]
__global__ __launch_bounds__(256) void pack_wih(const float* __restrict__ W,
                                                unsigned short* __restrict__ out) {
    int gid = blockIdx.x * 256 + threadIdx.x;        // 262144 total
    int lane = gid & 63, ks = (gid >> 6) & 15, p = gid >> 10;
    int c = lane & 15, quad = lane >> 4;
    int k = ks * 32 + quad * 8;
    int n = 0; bool valid = true;
    if (c < 4) n = p * 4 + c;
    else if (c < 8) n = H_ + p * 4 + (c - 4);
    else if (c < 12) n = 2 * H_ + p * 4 + (c - 8);
    else valid = false;
    const float* src = W + (size_t)n * I_ + k;
    u16x8 v;
#pragma unroll
    for (int jj = 0; jj < 8; jj++) v[jj] = valid ? f2bf(src[jj]) : (unsigned short)0;
    *(u16x8*)(out + (size_t)gid * 8) = v;
}

// Pack W_hh [3H, H] hi/lo into B-frag order: [p 256][ks 32][lane 64][8].
// Col 12 carries Wa_h (attention h-weights): hi part in bhi, lo in blo.
__global__ __launch_bounds__(256) void pack_whh(const float* __restrict__ W,
                                                const float* __restrict__ Watt,
                                                unsigned short* __restrict__ hi,
                                                unsigned short* __restrict__ lo) {
    int gid = blockIdx.x * 256 + threadIdx.x;        // 524288 total
    int lane = gid & 63, ks = (gid >> 6) & 31, p = gid >> 11;
    int c = lane & 15, quad = lane >> 4;
    int k = ks * 32 + quad * 8;
    u16x8 vh, vl;
#pragma unroll
    for (int jj = 0; jj < 8; jj++) {
        float f = 0.f;
        if (c < 4)        f = W[(size_t)(p * 4 + c) * H_ + k + jj];
        else if (c < 8)   f = W[(size_t)(H_ + p * 4 + (c - 4)) * H_ + k + jj];
        else if (c < 12)  f = W[(size_t)(2 * H_ + p * 4 + (c - 8)) * H_ + k + jj];
        else if (c == 12) f = Watt[I_ + k + jj];
        unsigned short h16 = f2bf(f);
        unsigned short l16 = f2bf(f - bf2f(h16));
        vh[jj] = h16; vl[jj] = l16;
    }
    *(u16x8*)(hi + (size_t)gid * 8) = vh;
    *(u16x8*)(lo + (size_t)gid * 8) = vl;
}

// Pack x into A-frag bf16 layout via LDS transpose: [t][m 8][ks 16][lane 64][8]
__global__ __launch_bounds__(256) void pack_x(const float* __restrict__ x,
                                              unsigned short* __restrict__ Gx) {
    int bid = blockIdx.x;                 // 2048 = 256 t * 8 m
    int t = bid >> 3, m = bid & 7;
    int tid = threadIdx.x;
    __shared__ unsigned short tile[16 * 520];
#pragma unroll
    for (int pass = 0; pass < 8; pass++) {
        int idx = pass * 256 + tid;
        int row = idx >> 7, c4 = idx & 127;
        float4 v = *(const float4*)(x + ((size_t)(m * 16 + row) * S_ + t) * I_ + c4 * 4);
        unsigned short* d = &tile[row * 520 + c4 * 4];
        d[0] = f2bf(v.x); d[1] = f2bf(v.y); d[2] = f2bf(v.z); d[3] = f2bf(v.w);
    }
    __syncthreads();
#pragma unroll
    for (int pass = 0; pass < 4; pass++) {
        int chunk = pass * 256 + tid;
        int ks = chunk >> 6, lane = chunk & 63;
        int c = lane & 15, kq = lane >> 4;
        int k = ks * 32 + kq * 8;
        u16x8 v = *(const u16x8*)(&tile[c * 520 + k]);
        *(u16x8*)(Gx + (((size_t)(t * 8 + m) * 16 + ks) * 64 + lane) * 8) = v;
    }
}

// sx[t*128+b] = x[b][t][:] . Wa_x  (fp32 exact)
__global__ __launch_bounds__(256) void sx_kernel(const float* __restrict__ x,
                                                 const float* __restrict__ Watt,
                                                 float* __restrict__ sx) {
    int t = blockIdx.x;
    int w = threadIdx.x >> 6, lane = threadIdx.x & 63;
    float4 wa0 = *(const float4*)(Watt + lane * 8);
    float4 wa1 = *(const float4*)(Watt + lane * 8 + 4);
    for (int i = 0; i < 32; i++) {
        int b = w * 32 + i;
        const float4* xp = (const float4*)(x + ((size_t)b * S_ + t) * I_ + lane * 8);
        float4 a0 = xp[0], a1 = xp[1];
        float s = a0.x * wa0.x + a0.y * wa0.y + a0.z * wa0.z + a0.w * wa0.w
                + a1.x * wa1.x + a1.y * wa1.y + a1.z * wa1.z + a1.w * wa1.w;
#pragma unroll
        for (int off = 1; off < 64; off <<= 1) s += __shfl_xor(s, off, 64);
        if (lane == 0) sx[t * 128 + b] = s;
    }
}

// ---------------------------------------------------------------------------
// Persistent recurrence, 256 blocks x 1024 thr (16 waves = 4/SIMD).
// K-SPLIT for TLP: waves 0-7 ("lower", w = wave) do gh over ks 0..15 and all
// of the epilogue (softmax/gates/stores). Waves 8-15 ("upper", same m-tile
// w-8) do gh over ks 16..31 PLUS the whole gi (x-frag stream, 16 MFMAs),
// then export f32x4 partials (gh, gi) through LDS. Halves per-wave load
// counts (80 -> 32..48) while doubling waves/SIMD -> 2-4x loads in flight.
// Next-step x-frags + sx are issued BEFORE the grid barrier (immutable data;
// latency hides under barrier wait). h loads stay after the barrier.
// Numerics identical to round 1 (same MFMA chains, fp32 combine).
// ---------------------------------------------------------------------------
__global__ __launch_bounds__(1024, 4) void gru_persist(
        const unsigned short* __restrict__ Gx,
        const float* __restrict__ sx,
        const unsigned short* __restrict__ WihP,
        const unsigned short* __restrict__ WhhHiP,
        const unsigned short* __restrict__ WhhLoP,
        unsigned short* __restrict__ Hhi,
        unsigned short* __restrict__ Hlo,
        const float* __restrict__ batt,
        const float* __restrict__ bih, const float* __restrict__ bhh,
        float* __restrict__ out, unsigned* __restrict__ bar) {
    int p = blockIdx.x;
    int tid = threadIdx.x, w16 = tid >> 6, lane = tid & 63;
    const bool upper = (w16 >= 8);
    int w = upper ? (w16 - 8) : w16;
    int quad = lane >> 4, c = lane & 15, cl = c & 3;

    __shared__ unsigned short bhi[16384];     // 32 KB [ks 32][lane 64][8]
    __shared__ unsigned short blo[16384];     // 32 KB
    __shared__ unsigned short wih_lds[8192];  // 16 KB [ks 16][lane 64][8]
    __shared__ f32x4 part_gh[8][64];          // 8 KB upper -> lower gh partial
    __shared__ f32x4 part_gi[8][64];          // 8 KB upper -> lower gi
    __shared__ float sh_lds[128];
    __shared__ float score_lds[128];

    {
        const uint4* s0 = (const uint4*)(WhhHiP + (size_t)p * 16384);
        uint4* d0 = (uint4*)bhi;
        for (int i = tid; i < 2048; i += 1024) d0[i] = s0[i];
        const uint4* s1 = (const uint4*)(WhhLoP + (size_t)p * 16384);
        uint4* d1 = (uint4*)blo;
        for (int i = tid; i < 2048; i += 1024) d1[i] = s1[i];
        const uint4* s2 = (const uint4*)(WihP + (size_t)p * 8192);
        ((uint4*)wih_lds)[tid] = s2[tid];
    }
    float ba = batt[0];
    int j = p * 4 + cl;
    float bihr = 0.f, bihz = 0.f, bihn = 0.f, bhhr = 0.f, bhhz = 0.f, bhhn = 0.f;
    if (!upper) {
        bihr = bih[j]; bihz = bih[H_ + j]; bihn = bih[2 * H_ + j];
        bhhr = bhh[j]; bhhz = bhh[H_ + j]; bhhn = bhh[2 * H_ + j];
    }
    __syncthreads();

    float hprev[4] = {0.f, 0.f, 0.f, 0.f};
    // h-store address components (lanes c<4): k32 = (p&7)*4+cl, j_e = k32&7.
    int k32 = (p & 7) * 4 + cl;
    int j_e = k32 & 7;
    size_t chunk_base = ((size_t)w * 32 + (size_t)(p >> 3)) * 64
                      + (size_t)(quad * 4) + 16 * (size_t)(k32 >> 3);

    // x-frag ring (upper waves own the gi stream); prologue for t=0
    u16x8 px[8];
    if (upper) {
        const unsigned short* xab0 = Gx + (size_t)w * 8192 + (size_t)lane * 8;
#pragma unroll
        for (int s = 0; s < 8; s++) px[s] = *(const u16x8*)(xab0 + s * 512);
    }
    float sxv = (tid < 128) ? sx[tid] : 0.f;    // t=0 (prefetched thereafter)

    for (int t = 0; t < S_; t++) {
        const unsigned short* hchi = Hhi + (size_t)t * 131072;
        const unsigned short* hclo = Hlo + (size_t)t * 131072;
        unsigned* hnhi32 = (unsigned*)(Hhi + (size_t)(t + 1) * 131072);
        unsigned* hnlo32 = (unsigned*)(Hlo + (size_t)(t + 1) * 131072);

        f32x4 acc0 = (f32x4){0.f, 0.f, 0.f, 0.f};
        f32x4 acc1 = (f32x4){0.f, 0.f, 0.f, 0.f};
        f32x4 gh;

        if (!upper) {
            // ---- lower: gh over ks 0..15, ring depth 8 ----
            const unsigned short* ahb = hchi + (size_t)w * 16384 + (size_t)lane * 8;
            const unsigned short* alb = hclo + (size_t)w * 16384 + (size_t)lane * 8;
            u16x8 ph[8], pl8[8];
#pragma unroll
            for (int s = 0; s < 8; s++) {
                ph[s]  = *(const u16x8*)(ahb + s * 512);
                pl8[s] = *(const u16x8*)(alb + s * 512);
            }
#pragma unroll
            for (int ks = 0; ks < 16; ks++) {
                const int s = ks & 7;
                bf16x8 ah = __builtin_bit_cast(bf16x8, ph[s]);
                bf16x8 al = __builtin_bit_cast(bf16x8, pl8[s]);
                bf16x8 bh = *(const bf16x8*)(bhi + ((size_t)ks * 64 + lane) * 8);
                bf16x8 bl = *(const bf16x8*)(blo + ((size_t)ks * 64 + lane) * 8);
                if (ks & 1) {
                    acc1 = __builtin_amdgcn_mfma_f32_16x16x32_bf16(ah, bh, acc1, 0, 0, 0);
                    acc1 = __builtin_amdgcn_mfma_f32_16x16x32_bf16(al, bh, acc1, 0, 0, 0);
                    acc1 = __builtin_amdgcn_mfma_f32_16x16x32_bf16(ah, bl, acc1, 0, 0, 0);
                } else {
                    acc0 = __builtin_amdgcn_mfma_f32_16x16x32_bf16(ah, bh, acc0, 0, 0, 0);
                    acc0 = __builtin_amdgcn_mfma_f32_16x16x32_bf16(al, bh, acc0, 0, 0, 0);
                    acc0 = __builtin_amdgcn_mfma_f32_16x16x32_bf16(ah, bl, acc0, 0, 0, 0);
                }
                if (ks < 8) {
                    ph[s]  = *(const u16x8*)(ahb + (ks + 8) * 512);
                    pl8[s] = *(const u16x8*)(alb + (ks + 8) * 512);
                }
            }
        } else {
            // ---- upper: gh over ks 16..31 (ring 4) + all of gi (x ring 8) ----
            const unsigned short* ahb = hchi + (size_t)w * 16384 + (size_t)lane * 8 + 16 * 512;
            const unsigned short* alb = hclo + (size_t)w * 16384 + (size_t)lane * 8 + 16 * 512;
            const unsigned short* xab = Gx + (size_t)t * 65536 + (size_t)w * 8192
                                           + (size_t)lane * 8;
            f32x4 accg = (f32x4){0.f, 0.f, 0.f, 0.f};
            u16x8 ph[4], pl8[4];
#pragma unroll
            for (int s = 0; s < 4; s++) {
                ph[s]  = *(const u16x8*)(ahb + s * 512);
                pl8[s] = *(const u16x8*)(alb + s * 512);
            }
#pragma unroll
            for (int kk = 0; kk < 16; kk++) {
                const int s = kk & 3;
                const int ks = 16 + kk;
                bf16x8 ah = __builtin_bit_cast(bf16x8, ph[s]);
                bf16x8 al = __builtin_bit_cast(bf16x8, pl8[s]);
                bf16x8 bh = *(const bf16x8*)(bhi + ((size_t)ks * 64 + lane) * 8);
                bf16x8 bl = *(const bf16x8*)(blo + ((size_t)ks * 64 + lane) * 8);
                bf16x8 xa = __builtin_bit_cast(bf16x8, px[kk & 7]);
                bf16x8 wb = *(const bf16x8*)(wih_lds + ((size_t)kk * 64 + lane) * 8);
                accg = __builtin_amdgcn_mfma_f32_16x16x32_bf16(xa, wb, accg, 0, 0, 0);
                if (kk & 1) {
                    acc1 = __builtin_amdgcn_mfma_f32_16x16x32_bf16(ah, bh, acc1, 0, 0, 0);
                    acc1 = __builtin_amdgcn_mfma_f32_16x16x32_bf16(al, bh, acc1, 0, 0, 0);
                    acc1 = __builtin_amdgcn_mfma_f32_16x16x32_bf16(ah, bl, acc1, 0, 0, 0);
                } else {
                    acc0 = __builtin_amdgcn_mfma_f32_16x16x32_bf16(ah, bh, acc0, 0, 0, 0);
                    acc0 = __builtin_amdgcn_mfma_f32_16x16x32_bf16(al, bh, acc0, 0, 0, 0);
                    acc0 = __builtin_amdgcn_mfma_f32_16x16x32_bf16(ah, bl, acc0, 0, 0, 0);
                }
                if (kk < 8) px[kk & 7] = *(const u16x8*)(xab + (kk + 8) * 512);
                if (kk < 12) {
                    ph[s]  = *(const u16x8*)(ahb + (kk + 4) * 512);
                    pl8[s] = *(const u16x8*)(alb + (kk + 4) * 512);
                }
            }
            // issue NEXT step's x prologue now (immutable; hides under barrier)
            int tn = (t + 1 < S_) ? (t + 1) : t;
            const unsigned short* xabn = Gx + (size_t)tn * 65536 + (size_t)w * 8192
                                            + (size_t)lane * 8;
#pragma unroll
            for (int s = 0; s < 8; s++) px[s] = *(const u16x8*)(xabn + s * 512);
            f32x4 gsum;
#pragma unroll
            for (int r = 0; r < 4; r++) gsum[r] = acc0[r] + acc1[r];
            part_gh[w][lane] = gsum;
            part_gi[w][lane] = accg;
        }
        __syncthreads();                       // partials ready

        f32x4 pi;
        if (!upper) {
            f32x4 pg = part_gh[w][lane];
            pi = part_gi[w][lane];
#pragma unroll
            for (int r = 0; r < 4; r++) gh[r] = acc0[r] + acc1[r] + pg[r];
            if (c == 12) {
#pragma unroll
                for (int r = 0; r < 4; r++) sh_lds[w * 16 + quad * 4 + r] = gh[r];
            }
        }
        __syncthreads();                       // sh ready
        if (tid < 128) score_lds[tid] = sh_lds[tid] + sxv + ba;
        __syncthreads();                       // scores ready

        if (!upper) {
            // ---- softmax stats (per lower wave, redundant) ----
            float s0 = score_lds[lane], s1 = score_lds[lane + 64];
            float mx = fmaxf(s0, s1);
#pragma unroll
            for (int off = 1; off < 64; off <<= 1) mx = fmaxf(mx, __shfl_xor(mx, off, 64));
            float pe = __expf(s0 - mx) + __expf(s1 - mx);
#pragma unroll
            for (int off = 1; off < 64; off <<= 1) pe += __shfl_xor(pe, off, 64);
            float rden = 1.f / pe;

            // ---- gates (C layout: col=lane&15, row=quad*4+r) ----
#pragma unroll
            for (int r = 0; r < 4; r++) {
                int b = w * 16 + quad * 4 + r;
                float att = __expf(score_lds[b] - mx) * rden;
                float ghr = gh[r];
                float ghz = __shfl_xor(ghr, 4, 64);
                float ghn = __shfl_xor(ghr, 8, 64);
                float gir = pi[r];
                float giz = __shfl_xor(gir, 4, 64);
                float gin = __shfl_xor(gir, 8, 64);
                float rg = 1.f / (1.f + __expf(-(att * gir + bihr + ghr + bhhr)));
                float zg = 1.f / (1.f + __expf(-(att * giz + bihz + ghz + bhhz)));
                float ta = att * gin + bihn + rg * (ghn + bhhn);
                ta = fminf(fmaxf(ta, -15.f), 15.f);   // tanh via exp, overflow-safe
                float e2 = __expf(2.f * ta);
                float ng = (e2 - 1.f) / (e2 + 1.f);
                float hnew = (1.f - zg) * ng + zg * hprev[r];
                hprev[r] = hnew;
                if (c < 4) {
                    out[((size_t)b * S_ + t) * H_ + j] = hnew;
                    unsigned short hi16 = f2bf(hnew);
                    unsigned short lo16 = f2bf(hnew - bf2f(hi16));
                    unsigned hval = (unsigned)hi16 | ((unsigned)lo16 << 16);
                    unsigned nb = __shfl_xor(hval, 1, 64);   // partner cl^1
                    if (!(cl & 1)) {
                        unsigned hipair = (hval & 0xffffu) | (nb << 16);
                        unsigned lopair = (hval >> 16) | (nb & 0xffff0000u);
                        unsigned* dh = hnhi32 + (chunk_base + r) * 4 + (j_e >> 1);
                        unsigned* dl = hnlo32 + (chunk_base + r) * 4 + (j_e >> 1);
                        asm volatile("global_store_dword %0, %1, off sc0 sc1"
                                     :: "v"(dh), "v"(hipair) : "memory");
                        asm volatile("global_store_dword %0, %1, off sc0 sc1"
                                     :: "v"(dl), "v"(lopair) : "memory");
                    }
                }
            }
        }
        // prefetch next sx (immutable; hides under barrier)
        if (tid < 128) {
            int tn = (t + 1 < S_) ? (t + 1) : t;
            sxv = sx[tn * 128 + tid];
        }

        if (t + 1 < S_) {
            // ---- grid barrier: drain stores, arrive, parallel 8-lane poll ----
            __syncthreads();     // vmcnt(0): every wave's sc0sc1 stores drained
            if (tid < 64) {
                if (lane == 0)
                    __hip_atomic_fetch_add(bar + (p & 7) * 32, 1u,
                                           __ATOMIC_RELAXED, __HIP_MEMORY_SCOPE_AGENT);
                unsigned tgt = (unsigned)(t + 1) * 32u;   // 256 blocks / 8 counters
                for (;;) {
                    unsigned v = tgt;
                    if (lane < 8)
                        v = __hip_atomic_load(bar + lane * 32, __ATOMIC_RELAXED,
                                              __HIP_MEMORY_SCOPE_AGENT);
                    if (__all(v >= tgt)) break;
                    __builtin_amdgcn_s_sleep(1);
                }
            }
            __syncthreads();
        }
    }

    // final hidden state
    if (!upper && c < 4) {
#pragma unroll
        for (int r = 0; r < 4; r++)
            out[(size_t)B_ * S_ * H_ + (size_t)(w * 16 + quad * 4 + r) * H_ + j] = hprev[r];
    }
}

// ---------------------------------------------------------------------------
extern "C" void kernel_launch(void* const* d_in, const int* in_sizes, int n_in,
                              void* d_out, int out_size, void* d_ws, size_t ws_size,
                              hipStream_t stream) {
    (void)in_sizes; (void)n_in; (void)out_size; (void)ws_size;
    const float* x    = (const float*)d_in[0];
    const float* Watt = (const float*)d_in[1];
    const float* batt = (const float*)d_in[2];
    const float* Wih  = (const float*)d_in[3];
    const float* Whh  = (const float*)d_in[4];
    const float* bih  = (const float*)d_in[5];
    const float* bhh  = (const float*)d_in[6];
    float* out = (float*)d_out;

    char* ws = (char*)d_ws;
    size_t off = 0;
    unsigned short* Gx     = (unsigned short*)(ws + off); off += 33554432ULL;   // 32 MB
    unsigned short* WihP   = (unsigned short*)(ws + off); off += 4194304ULL;    // 4 MB
    unsigned short* WhhHiP = (unsigned short*)(ws + off); off += 8388608ULL;    // 8 MB
    unsigned short* WhhLoP = (unsigned short*)(ws + off); off += 8388608ULL;    // 8 MB
    float*          sx     = (float*)(ws + off);          off += 131072ULL;
    unsigned short* Hhi    = (unsigned short*)(ws + off); off += 67371008ULL;   // 257*256 KB
    unsigned short* Hlo    = (unsigned short*)(ws + off); off += 67371008ULL;   // 257*256 KB
    unsigned*       bar    = (unsigned*)(ws + off);       off += 1024ULL;

    hipMemsetAsync(Hhi, 0, 262144, stream);    // step-0 h = 0
    hipMemsetAsync(Hlo, 0, 262144, stream);
    hipMemsetAsync(bar, 0, 1024, stream);
    pack_wih<<<1024, 256, 0, stream>>>(Wih, WihP);
    pack_whh<<<2048, 256, 0, stream>>>(Whh, Watt, WhhHiP, WhhLoP);
    pack_x<<<2048, 256, 0, stream>>>(x, Gx);
    sx_kernel<<<256, 256, 0, stream>>>(x, Watt, sx);
    gru_persist<<<256, 1024, 0, stream>>>(Gx, sx, WihP, WhhHiP, WhhLoP, Hhi, Hlo,
                                          batt, bih, bhh, out, bar);
}

// Round 4
// 3087.996 us; speedup vs baseline: 1.1941x; 1.1941x over previous
//
#include <hip/hip_runtime.h>
#include <hip/hip_bf16.h>

#define B_ 128
#define S_ 256
#define I_ 512
#define H_ 1024

typedef float  f32x4  __attribute__((ext_vector_type(4)));
typedef __bf16 bf16x8 __attribute__((ext_vector_type(8)));
typedef unsigned short u16x8 __attribute__((ext_vector_type(8)));

__device__ __forceinline__ unsigned short f2bf(float f) {
    unsigned u = __float_as_uint(f);
    unsigned r = (u + 0x7fffu + ((u >> 16) & 1u)) >> 16;   // RNE
    return (unsigned short)r;
}
__device__ __forceinline__ float bf2f(unsigned short s) {
    return __uint_as_float(((unsigned)s) << 16);
}

// ---------------------------------------------------------------------------
// Column mapping (4 h-cols per p, 256 p-groups): B/C tile col c:
//   c 0-3 -> r-gate row p*4+c ; c 4-7 -> z-gate H+... ; c 8-11 -> n-gate 2H+...
//   c 12 -> Wa_h (hi in bhi, lo in blo)  => acc col 12 = h . Wa_h  (sh)
//   c 13-15 -> zero pad.
// ---------------------------------------------------------------------------

// Pack W_ih [3H, I] into per-colgroup B-frag order: [p 256][ks 16][lane 64][8]
__global__ __launch_bounds__(256) void pack_wih(const float* __restrict__ W,
                                                unsigned short* __restrict__ out) {
    int gid = blockIdx.x * 256 + threadIdx.x;        // 262144 total
    int lane = gid & 63, ks = (gid >> 6) & 15, p = gid >> 10;
    int c = lane & 15, quad = lane >> 4;
    int k = ks * 32 + quad * 8;
    int n = 0; bool valid = true;
    if (c < 4) n = p * 4 + c;
    else if (c < 8) n = H_ + p * 4 + (c - 4);
    else if (c < 12) n = 2 * H_ + p * 4 + (c - 8);
    else valid = false;
    const float* src = W + (size_t)n * I_ + k;
    u16x8 v;
#pragma unroll
    for (int jj = 0; jj < 8; jj++) v[jj] = valid ? f2bf(src[jj]) : (unsigned short)0;
    *(u16x8*)(out + (size_t)gid * 8) = v;
}

// Pack W_hh [3H, H] hi/lo into B-frag order: [p 256][ks 32][lane 64][8].
// Col 12 carries Wa_h (attention h-weights): hi part in bhi, lo in blo.
__global__ __launch_bounds__(256) void pack_whh(const float* __restrict__ W,
                                                const float* __restrict__ Watt,
                                                unsigned short* __restrict__ hi,
                                                unsigned short* __restrict__ lo) {
    int gid = blockIdx.x * 256 + threadIdx.x;        // 524288 total
    int lane = gid & 63, ks = (gid >> 6) & 31, p = gid >> 11;
    int c = lane & 15, quad = lane >> 4;
    int k = ks * 32 + quad * 8;
    u16x8 vh, vl;
#pragma unroll
    for (int jj = 0; jj < 8; jj++) {
        float f = 0.f;
        if (c < 4)        f = W[(size_t)(p * 4 + c) * H_ + k + jj];
        else if (c < 8)   f = W[(size_t)(H_ + p * 4 + (c - 4)) * H_ + k + jj];
        else if (c < 12)  f = W[(size_t)(2 * H_ + p * 4 + (c - 8)) * H_ + k + jj];
        else if (c == 12) f = Watt[I_ + k + jj];
        unsigned short h16 = f2bf(f);
        unsigned short l16 = f2bf(f - bf2f(h16));
        vh[jj] = h16; vl[jj] = l16;
    }
    *(u16x8*)(hi + (size_t)gid * 8) = vh;
    *(u16x8*)(lo + (size_t)gid * 8) = vl;
}

// Pack x into A-frag bf16 layout via LDS transpose: [t][m 8][ks 16][lane 64][8]
__global__ __launch_bounds__(256) void pack_x(const float* __restrict__ x,
                                              unsigned short* __restrict__ Gx) {
    int bid = blockIdx.x;                 // 2048 = 256 t * 8 m
    int t = bid >> 3, m = bid & 7;
    int tid = threadIdx.x;
    __shared__ unsigned short tile[16 * 520];
#pragma unroll
    for (int pass = 0; pass < 8; pass++) {
        int idx = pass * 256 + tid;
        int row = idx >> 7, c4 = idx & 127;
        float4 v = *(const float4*)(x + ((size_t)(m * 16 + row) * S_ + t) * I_ + c4 * 4);
        unsigned short* d = &tile[row * 520 + c4 * 4];
        d[0] = f2bf(v.x); d[1] = f2bf(v.y); d[2] = f2bf(v.z); d[3] = f2bf(v.w);
    }
    __syncthreads();
#pragma unroll
    for (int pass = 0; pass < 4; pass++) {
        int chunk = pass * 256 + tid;
        int ks = chunk >> 6, lane = chunk & 63;
        int c = lane & 15, kq = lane >> 4;
        int k = ks * 32 + kq * 8;
        u16x8 v = *(const u16x8*)(&tile[c * 520 + k]);
        *(u16x8*)(Gx + (((size_t)(t * 8 + m) * 16 + ks) * 64 + lane) * 8) = v;
    }
}

// sx[t*128+b] = x[b][t][:] . Wa_x  (fp32 exact)
__global__ __launch_bounds__(256) void sx_kernel(const float* __restrict__ x,
                                                 const float* __restrict__ Watt,
                                                 float* __restrict__ sx) {
    int t = blockIdx.x;
    int w = threadIdx.x >> 6, lane = threadIdx.x & 63;
    float4 wa0 = *(const float4*)(Watt + lane * 8);
    float4 wa1 = *(const float4*)(Watt + lane * 8 + 4);
    for (int i = 0; i < 32; i++) {
        int b = w * 32 + i;
        const float4* xp = (const float4*)(x + ((size_t)b * S_ + t) * I_ + lane * 8);
        float4 a0 = xp[0], a1 = xp[1];
        float s = a0.x * wa0.x + a0.y * wa0.y + a0.z * wa0.z + a0.w * wa0.w
                + a1.x * wa1.x + a1.y * wa1.y + a1.z * wa1.z + a1.w * wa1.w;
#pragma unroll
        for (int off = 1; off < 64; off <<= 1) s += __shfl_xor(s, off, 64);
        if (lane == 0) sx[t * 128 + b] = s;
    }
}

// ---------------------------------------------------------------------------
// Persistent recurrence (round-1 shape: 256 blocks x 512 thr, 8 waves = m).
// Round-4 changes vs round-1 (3150us):
//   * h-hi / h-lo / x streams staged via __builtin_amdgcn_global_load_lds
//     into a per-wave 3-slot LDS ring (slot = 3 KB: hi 1K | lo 1K | x 1K),
//     drained with counted s_waitcnt vmcnt(N). Data never touches VGPRs on
//     the way in -> compiler cannot collapse the pipeline (round-1 VGPR=88
//     proved it collapsed the register ring). 6-9 DMAs in flight per wave.
//   * ALL in-loop VMEM is these DMAs (x no longer register-preloaded), so
//     the manual vmcnt counts are exact; every iter opens with a
//     memory-clobber asm so compiler memory ops can't migrate inside.
//   * registerized softmax: sh broadcast from col 12 by in-wave shuffle,
//     per-wave (max,expsum) partials -> LDS -> ONE syncthreads -> combine.
//   * slot WAR (refill DMA overwrites just-read slot): safe by timing --
//     ds_read completes ~120cy, DMA data returns >=200cy after issue.
// LDS: bhi 32K + blo 32K + wih 16K + hstage 72K = 152 KB (1 block/CU).
// Stores / grid barrier / workspace identical to round 1 (proven).
// ---------------------------------------------------------------------------
__global__ __launch_bounds__(512) void gru_persist(
        const unsigned short* __restrict__ Gx,
        const float* __restrict__ sx,
        const unsigned short* __restrict__ WihP,
        const unsigned short* __restrict__ WhhHiP,
        const unsigned short* __restrict__ WhhLoP,
        unsigned short* __restrict__ Hhi,
        unsigned short* __restrict__ Hlo,
        const float* __restrict__ batt,
        const float* __restrict__ bih, const float* __restrict__ bhh,
        float* __restrict__ out, unsigned* __restrict__ bar) {
    int p = blockIdx.x;
    int tid = threadIdx.x, w = tid >> 6, lane = tid & 63;
    int quad = lane >> 4, c = lane & 15, cl = c & 3;

    __shared__ unsigned short bhi[16384];     // 32 KB [ks 32][lane 64][8]
    __shared__ unsigned short blo[16384];     // 32 KB
    __shared__ unsigned short wih_lds[8192];  // 16 KB [ks 16][lane 64][8]
    __shared__ unsigned short hstage[36864];  // 72 KB [w 8][slot 3][1536]
    __shared__ float2 swr[8];                 // per-wave (max, expsum)

    {
        const uint4* s0 = (const uint4*)(WhhHiP + (size_t)p * 16384);
        uint4* d0 = (uint4*)bhi;
        for (int i = tid; i < 2048; i += 512) d0[i] = s0[i];
        const uint4* s1 = (const uint4*)(WhhLoP + (size_t)p * 16384);
        uint4* d1 = (uint4*)blo;
        for (int i = tid; i < 2048; i += 512) d1[i] = s1[i];
        const uint4* s2 = (const uint4*)(WihP + (size_t)p * 8192);
        uint4* d2 = (uint4*)wih_lds;
        for (int i = tid; i < 1024; i += 512) d2[i] = s2[i];
    }
    float ba = batt[0];
    int j = p * 4 + cl;
    float bihr = bih[j], bihz = bih[H_ + j], bihn = bih[2 * H_ + j];
    float bhhr = bhh[j], bhhz = bhh[H_ + j], bhhn = bhh[2 * H_ + j];
    __syncthreads();

    float hprev[4] = {0.f, 0.f, 0.f, 0.f};
    // h-store address components (lanes c<4): k32 = (p&7)*4+cl, j_e = k32&7.
    int k32 = (p & 7) * 4 + cl;
    int j_e = k32 & 7;
    size_t chunk_base = ((size_t)w * 32 + (size_t)(p >> 3)) * 64
                      + (size_t)(quad * 4) + 16 * (size_t)(k32 >> 3);

    int b0r = w * 16 + quad * 4;
    unsigned short* stg = hstage + (size_t)w * 4608;   // 3 slots * 1536 u16

    // sx for t=0 (prefetched at end of each step thereafter)
    float sxr[4];
#pragma unroll
    for (int r = 0; r < 4; r++) sxr[r] = sx[b0r + r];

    for (int t = 0; t < S_; t++) {
        const unsigned short* hbhi = Hhi + (size_t)t * 131072 + (size_t)w * 16384
                                         + (size_t)lane * 8;
        const unsigned short* hblo = Hlo + (size_t)t * 131072 + (size_t)w * 16384
                                         + (size_t)lane * 8;
        const unsigned short* xb   = Gx + (size_t)t * 65536 + (size_t)w * 8192
                                        + (size_t)lane * 8;
        unsigned* hnhi32 = (unsigned*)(Hhi + (size_t)(t + 1) * 131072);
        unsigned* hnlo32 = (unsigned*)(Hlo + (size_t)(t + 1) * 131072);

        // ---- DMA prologue: stage slots 0..2 (ks = 0,1,2 : hi, lo, x) ----
#pragma unroll
        for (int k = 0; k < 3; k++) {
            unsigned short* d = stg + k * 1536;
            __builtin_amdgcn_global_load_lds((const unsigned int*)(hbhi + k * 512),
                                             (unsigned int*)(d), 16, 0, 0);
            __builtin_amdgcn_global_load_lds((const unsigned int*)(hblo + k * 512),
                                             (unsigned int*)(d + 512), 16, 0, 0);
            __builtin_amdgcn_global_load_lds((const unsigned int*)(xb + k * 512),
                                             (unsigned int*)(d + 1024), 16, 0, 0);
        }

        f32x4 accg = (f32x4){0.f, 0.f, 0.f, 0.f};
        f32x4 acc0 = (f32x4){0.f, 0.f, 0.f, 0.f};
        f32x4 acc1 = (f32x4){0.f, 0.f, 0.f, 0.f};
#pragma unroll
        for (int ks = 0; ks < 32; ks++) {
            const int slot = ks % 3;
            // wait for slot ks's DMAs. op(k) = 3 (k<16: hi,lo,x) else 2.
            // outstanding at top = ops of slots ks..min(ks+2,31); target =
            // outstanding - op(ks).
            if (ks <= 13)      asm volatile("s_waitcnt vmcnt(6)" ::: "memory");
            else if (ks == 14) asm volatile("s_waitcnt vmcnt(5)" ::: "memory");
            else if (ks <= 29) asm volatile("s_waitcnt vmcnt(4)" ::: "memory");
            else if (ks == 30) asm volatile("s_waitcnt vmcnt(2)" ::: "memory");
            else               asm volatile("s_waitcnt vmcnt(0)" ::: "memory");

            const unsigned short* sb = stg + slot * 1536;
            bf16x8 ah = *(const bf16x8*)(sb + (size_t)lane * 8);
            bf16x8 al = *(const bf16x8*)(sb + 512 + (size_t)lane * 8);
            bf16x8 bh = *(const bf16x8*)(bhi + ((size_t)ks * 64 + lane) * 8);
            bf16x8 bl = *(const bf16x8*)(blo + ((size_t)ks * 64 + lane) * 8);
            if (ks < 16) {
                bf16x8 xa = *(const bf16x8*)(sb + 1024 + (size_t)lane * 8);
                bf16x8 wb = *(const bf16x8*)(wih_lds + ((size_t)ks * 64 + lane) * 8);
                accg = __builtin_amdgcn_mfma_f32_16x16x32_bf16(xa, wb, accg, 0, 0, 0);
            }
            if (ks & 1) {
                acc1 = __builtin_amdgcn_mfma_f32_16x16x32_bf16(ah, bh, acc1, 0, 0, 0);
                acc1 = __builtin_amdgcn_mfma_f32_16x16x32_bf16(al, bh, acc1, 0, 0, 0);
                acc1 = __builtin_amdgcn_mfma_f32_16x16x32_bf16(ah, bl, acc1, 0, 0, 0);
            } else {
                acc0 = __builtin_amdgcn_mfma_f32_16x16x32_bf16(ah, bh, acc0, 0, 0, 0);
                acc0 = __builtin_amdgcn_mfma_f32_16x16x32_bf16(al, bh, acc0, 0, 0, 0);
                acc0 = __builtin_amdgcn_mfma_f32_16x16x32_bf16(ah, bl, acc0, 0, 0, 0);
            }
            // refill this slot with ks+3
            const int k2 = ks + 3;
            if (k2 < 32) {
                unsigned short* d = stg + slot * 1536;
                __builtin_amdgcn_global_load_lds((const unsigned int*)(hbhi + k2 * 512),
                                                 (unsigned int*)(d), 16, 0, 0);
                __builtin_amdgcn_global_load_lds((const unsigned int*)(hblo + k2 * 512),
                                                 (unsigned int*)(d + 512), 16, 0, 0);
                if (k2 < 16)
                    __builtin_amdgcn_global_load_lds((const unsigned int*)(xb + k2 * 512),
                                                     (unsigned int*)(d + 1024), 16, 0, 0);
            }
        }

        f32x4 gh;
#pragma unroll
        for (int r = 0; r < 4; r++) gh[r] = acc0[r] + acc1[r];

        // ---- registerized softmax: broadcast sh (col 12) in-wave ----
        float sc[4];
#pragma unroll
        for (int r = 0; r < 4; r++) {
            float shr = __shfl(gh[r], (lane & 0x30) + 12, 64);
            sc[r] = shr + sxr[r] + ba;
        }
        float mw = fmaxf(fmaxf(sc[0], sc[1]), fmaxf(sc[2], sc[3]));
        mw = fmaxf(mw, __shfl_xor(mw, 16, 64));
        mw = fmaxf(mw, __shfl_xor(mw, 32, 64));
        float ew = __expf(sc[0] - mw) + __expf(sc[1] - mw)
                 + __expf(sc[2] - mw) + __expf(sc[3] - mw);
        ew += __shfl_xor(ew, 16, 64);
        ew += __shfl_xor(ew, 32, 64);
        if (lane == 0) swr[w] = (float2){mw, ew};
        __syncthreads();
        float mx = swr[0].x;
#pragma unroll
        for (int i = 1; i < 8; i++) mx = fmaxf(mx, swr[i].x);
        float pe = 0.f;
#pragma unroll
        for (int i = 0; i < 8; i++) pe += swr[i].y * __expf(swr[i].x - mx);
        float rden = 1.f / pe;

        // ---- gates (C layout: col=lane&15, row=quad*4+r) ----
#pragma unroll
        for (int r = 0; r < 4; r++) {
            int b = b0r + r;
            float att = __expf(sc[r] - mx) * rden;
            float ghr = gh[r];
            float ghz = __shfl_xor(ghr, 4, 64);
            float ghn = __shfl_xor(ghr, 8, 64);
            float gir = accg[r];
            float giz = __shfl_xor(gir, 4, 64);
            float gin = __shfl_xor(gir, 8, 64);
            float rg = 1.f / (1.f + __expf(-(att * gir + bihr + ghr + bhhr)));
            float zg = 1.f / (1.f + __expf(-(att * giz + bihz + ghz + bhhz)));
            float ta = att * gin + bihn + rg * (ghn + bhhn);
            ta = fminf(fmaxf(ta, -15.f), 15.f);   // tanh via exp, overflow-safe
            float e2 = __expf(2.f * ta);
            float ng = (e2 - 1.f) / (e2 + 1.f);
            float hnew = (1.f - zg) * ng + zg * hprev[r];
            hprev[r] = hnew;
            if (c < 4) {
                out[((size_t)b * S_ + t) * H_ + j] = hnew;
                unsigned short hi16 = f2bf(hnew);
                unsigned short lo16 = f2bf(hnew - bf2f(hi16));
                unsigned hval = (unsigned)hi16 | ((unsigned)lo16 << 16);
                unsigned nb = __shfl_xor(hval, 1, 64);   // partner cl^1
                if (!(cl & 1)) {
                    unsigned hipair = (hval & 0xffffu) | (nb << 16);
                    unsigned lopair = (hval >> 16) | (nb & 0xffff0000u);
                    unsigned* dh = hnhi32 + (chunk_base + r) * 4 + (j_e >> 1);
                    unsigned* dl = hnlo32 + (chunk_base + r) * 4 + (j_e >> 1);
                    asm volatile("global_store_dword %0, %1, off sc0 sc1"
                                 :: "v"(dh), "v"(hipair) : "memory");
                    asm volatile("global_store_dword %0, %1, off sc0 sc1"
                                 :: "v"(dl), "v"(lopair) : "memory");
                }
            }
        }

        // ---- prefetch t+1 sx (immutable; hides under barrier wait) ----
        {
            int tn = (t + 1 < S_) ? (t + 1) : t;
#pragma unroll
            for (int r = 0; r < 4; r++) sxr[r] = sx[tn * 128 + b0r + r];
        }

        if (t + 1 < S_) {
            // ---- grid barrier: drain stores, arrive, parallel 8-lane poll ----
            __syncthreads();     // vmcnt(0): every wave's sc0sc1 stores drained
            if (tid < 64) {
                if (lane == 0)
                    __hip_atomic_fetch_add(bar + (p & 7) * 32, 1u,
                                           __ATOMIC_RELAXED, __HIP_MEMORY_SCOPE_AGENT);
                unsigned tgt = (unsigned)(t + 1) * 32u;   // 256 blocks / 8 counters
                for (;;) {
                    unsigned v = tgt;
                    if (lane < 8)
                        v = __hip_atomic_load(bar + lane * 32, __ATOMIC_RELAXED,
                                              __HIP_MEMORY_SCOPE_AGENT);
                    if (__all(v >= tgt)) break;
                    __builtin_amdgcn_s_sleep(1);
                }
            }
            __syncthreads();
        }
    }

    // final hidden state
    if (c < 4) {
#pragma unroll
        for (int r = 0; r < 4; r++)
            out[(size_t)B_ * S_ * H_ + (size_t)(b0r + r) * H_ + j] = hprev[r];
    }
}

// ---------------------------------------------------------------------------
extern "C" void kernel_launch(void* const* d_in, const int* in_sizes, int n_in,
                              void* d_out, int out_size, void* d_ws, size_t ws_size,
                              hipStream_t stream) {
    (void)in_sizes; (void)n_in; (void)out_size; (void)ws_size;
    const float* x    = (const float*)d_in[0];
    const float* Watt = (const float*)d_in[1];
    const float* batt = (const float*)d_in[2];
    const float* Wih  = (const float*)d_in[3];
    const float* Whh  = (const float*)d_in[4];
    const float* bih  = (const float*)d_in[5];
    const float* bhh  = (const float*)d_in[6];
    float* out = (float*)d_out;

    char* ws = (char*)d_ws;
    size_t off = 0;
    unsigned short* Gx     = (unsigned short*)(ws + off); off += 33554432ULL;   // 32 MB
    unsigned short* WihP   = (unsigned short*)(ws + off); off += 4194304ULL;    // 4 MB
    unsigned short* WhhHiP = (unsigned short*)(ws + off); off += 8388608ULL;    // 8 MB
    unsigned short* WhhLoP = (unsigned short*)(ws + off); off += 8388608ULL;    // 8 MB
    float*          sx     = (float*)(ws + off);          off += 131072ULL;
    unsigned short* Hhi    = (unsigned short*)(ws + off); off += 67371008ULL;   // 257*256 KB
    unsigned short* Hlo    = (unsigned short*)(ws + off); off += 67371008ULL;   // 257*256 KB
    unsigned*       bar    = (unsigned*)(ws + off);       off += 1024ULL;

    hipMemsetAsync(Hhi, 0, 262144, stream);    // step-0 h = 0
    hipMemsetAsync(Hlo, 0, 262144, stream);
    hipMemsetAsync(bar, 0, 1024, stream);
    pack_wih<<<1024, 256, 0, stream>>>(Wih, WihP);
    pack_whh<<<2048, 256, 0, stream>>>(Whh, Watt, WhhHiP, WhhLoP);
    pack_x<<<2048, 256, 0, stream>>>(x, Gx);
    sx_kernel<<<256, 256, 0, stream>>>(x, Watt, sx);
    gru_persist<<<256, 512, 0, stream>>>(Gx, sx, WihP, WhhHiP, WhhLoP, Hhi, Hlo,
                                         batt, bih, bhh, out, bar);
}